// Round 1
// baseline (3068.784 us; speedup 1.0000x reference)
//
#include <hip/hip_runtime.h>

#define DIM 64
#define BOT 15
#define NLAYERS 5
#define BN_EPS 1e-5f
#define ROWS 32
#define THREADS 256

// ---------------- CSR build ----------------

__global__ __launch_bounds__(256) void hist_k(const int* __restrict__ dst,
                                              int* __restrict__ deg, int E) {
    int e = blockIdx.x * blockDim.x + threadIdx.x;
    if (e < E) atomicAdd(&deg[dst[e]], 1);
}

// single-block exclusive scan; deg is read and overwritten with the exclusive
// prefix (used as the scatter cursor); row_ptr gets the same + row_ptr[n]=total
__global__ __launch_bounds__(1024) void scan_k(int* __restrict__ deg,
                                               int* __restrict__ row_ptr, int n) {
    __shared__ int buf[1024];
    __shared__ int carry_s;
    int t = threadIdx.x;
    if (t == 0) carry_s = 0;
    __syncthreads();
    for (int base = 0; base < n; base += 1024) {
        int idx = base + t;
        int v = (idx < n) ? deg[idx] : 0;
        buf[t] = v;
        __syncthreads();
        for (int off = 1; off < 1024; off <<= 1) {
            int x = (t >= off) ? buf[t - off] : 0;
            __syncthreads();
            buf[t] += x;
            __syncthreads();
        }
        int c = carry_s;
        int excl = c + buf[t] - v;
        if (idx < n) { row_ptr[idx] = excl; deg[idx] = excl; }
        int total = buf[1023];
        __syncthreads();
        if (t == 0) carry_s = c + total;
        __syncthreads();
    }
    if (t == 0) row_ptr[n] = carry_s;
}

__global__ __launch_bounds__(256) void scatter_k(const int* __restrict__ src,
                                                 const int* __restrict__ dst,
                                                 int* __restrict__ cursor,
                                                 int* __restrict__ csr, int E) {
    int e = blockIdx.x * blockDim.x + threadIdx.x;
    if (e < E) {
        int p = atomicAdd(&cursor[dst[e]], 1);
        csr[p] = src[e];
    }
}

// ---------------- aggregation: one wave per node, lane = feature ----------------

__global__ __launch_bounds__(256) void aggr_k(const float* __restrict__ h,
                                              const int* __restrict__ row_ptr,
                                              const int* __restrict__ csr,
                                              float* __restrict__ out, int n) {
    int gid = blockIdx.x * blockDim.x + threadIdx.x;
    int node = gid >> 6;
    int lane = gid & 63;
    if (node >= n) return;
    int s = row_ptr[node], e = row_ptr[node + 1];
    float acc = 0.f;
    int i = s;
    for (; i + 4 <= e; i += 4) {
        int a = csr[i], b = csr[i + 1], c = csr[i + 2], d = csr[i + 3];
        float v0 = h[a * DIM + lane];
        float v1 = h[b * DIM + lane];
        float v2 = h[c * DIM + lane];
        float v3 = h[d * DIM + lane];
        acc += (v0 + v1) + (v2 + v3);
    }
    for (; i < e; ++i) acc += h[csr[i] * DIM + lane];
    out[node * DIM + lane] = acc;
}

// ---------------- fused per-layer compute ----------------
// MODE 0: compute t0/a0/a1 per row, accumulate per-column sum & sumsq -> partials
// MODE 1: recompute, apply precombined BN scale/shift (ST), write out
// MODE 2: same as 1 + ReLU

template <int MODE>
__global__ __launch_bounds__(THREADS) void layer_k(
    const float* __restrict__ h, const float* __restrict__ aggr,
    const float* __restrict__ Wc, const float* __restrict__ bc,
    const float* __restrict__ p1a, const float* __restrict__ b1a,
    const float* __restrict__ p2a, const float* __restrict__ b2a,
    const float* __restrict__ p1b, const float* __restrict__ b1b,
    const float* __restrict__ p2b, const float* __restrict__ b2b,
    float* __restrict__ partials, const float* __restrict__ ST,
    float* __restrict__ hout, int n) {
    __shared__ float xh[ROWS][DIM + 1];   // +1 pad: kills 8-way bank conflict in k-loop
    __shared__ float xa[ROWS][DIM + 1];
    __shared__ float m0[ROWS][17];
    __shared__ float m1[ROWS][17];
    __shared__ float red[6][4][DIM];

    int t = threadIdx.x;
    int rowBase = blockIdx.x * ROWS;

    // phase 0: stage 32 rows of h and aggr (coalesced)
    #pragma unroll
    for (int i = 0; i < (ROWS * DIM) / THREADS; i++) {
        int idx = t + i * THREADS;
        int r = idx >> 6, c = idx & 63;
        int gr = rowBase + r;
        float vh = 0.f, va = 0.f;
        if (gr < n) { vh = h[(size_t)gr * DIM + c]; va = aggr[(size_t)gr * DIM + c]; }
        xh[r][c] = vh;
        xa[r][c] = va;
    }
    __syncthreads();

    // phase 1: adapter bottleneck mids: relu(x @ w1 + b1), 15 per row per branch
    {
        int r = t >> 3, sub = t & 7;
        #pragma unroll
        for (int half = 0; half < 2; half++) {
            int m = sub + half * 8;
            if (m < BOT) {
                float s0 = b1a[m], s1 = b1b[m];
                #pragma unroll
                for (int k = 0; k < DIM; k++) {
                    s0 = fmaf(xh[r][k], p1a[k * BOT + m], s0);
                    s1 = fmaf(xa[r][k], p1b[k * BOT + m], s1);
                }
                m0[r][m] = fmaxf(s0, 0.f);
                m1[r][m] = fmaxf(s1, 0.f);
            }
        }
    }
    __syncthreads();

    // phase 2: per-element conv + adapter outputs
    int col = t & 63;
    int rg = t >> 6;
    float sums[6] = {0.f, 0.f, 0.f, 0.f, 0.f, 0.f};
    float S0 = 0, T0 = 0, S1 = 0, T1 = 0, S2 = 0, T2 = 0;
    if (MODE != 0) {
        S0 = ST[col];        T0 = ST[64 + col];
        S1 = ST[128 + col];  T1 = ST[192 + col];
        S2 = ST[256 + col];  T2 = ST[320 + col];
    }
    #pragma unroll
    for (int i = 0; i < ROWS / 4; i++) {
        int r = rg + i * 4;
        int gr = rowBase + r;
        float s = bc[col];
        #pragma unroll
        for (int k = 0; k < DIM; k++) s = fmaf(xa[r][k], Wc[k * DIM + col], s);
        float u = b2a[col];
        #pragma unroll
        for (int m = 0; m < BOT; m++) u = fmaf(m0[r][m], p2a[m * DIM + col], u);
        float v = b2b[col];
        #pragma unroll
        for (int m = 0; m < BOT; m++) v = fmaf(m1[r][m], p2b[m * DIM + col], v);
        if (MODE == 0) {
            if (gr < n) {
                sums[0] += s; sums[1] += s * s;
                sums[2] += u; sums[3] += u * u;
                sums[4] += v; sums[5] += v * v;
            }
        } else {
            float r0 = fmaf(s, S0, T0) + fmaf(u, S1, T1) + fmaf(v, S2, T2);
            if (MODE == 2) r0 = fmaxf(r0, 0.f);
            if (gr < n) hout[(size_t)gr * DIM + col] = r0;
        }
    }

    if (MODE == 0) {
        #pragma unroll
        for (int j = 0; j < 6; j++) red[j][rg][col] = sums[j];
        __syncthreads();
        if (t < DIM) {
            #pragma unroll
            for (int j = 0; j < 6; j++) {
                float v = red[j][0][t] + red[j][1][t] + red[j][2][t] + red[j][3][t];
                partials[((size_t)blockIdx.x * 6 + j) * DIM + t] = v;
            }
        }
    }
}

// ---------------- stats reduce + BN fold ----------------
// folds mean/var/gamma/beta/gating into per-column scale S and shift T:
//   bn(x)*gate = x*S + T,  S = g*rstd*gate,  T = (b - mean*g*rstd)*gate

__global__ __launch_bounds__(384) void reduce_k(
    const float* __restrict__ partials, int nb, int n,
    const float* __restrict__ bn_g, const float* __restrict__ bn_b,
    const float* __restrict__ pg0, const float* __restrict__ pb0,
    const float* __restrict__ pg1, const float* __restrict__ pb1,
    const float* __restrict__ gating, int l, float* __restrict__ ST) {
    __shared__ float sums[6][DIM];
    int t = threadIdx.x;
    int j = t >> 6, col = t & 63;
    double acc = 0.0;
    for (int b2 = 0; b2 < nb; b2++)
        acc += (double)partials[((size_t)b2 * 6 + j) * DIM + col];
    sums[j][col] = (float)acc;
    __syncthreads();
    if (t < 192) {
        int stat = t >> 6;
        int c = t & 63;
        float mean = sums[2 * stat][c] / (float)n;
        float var = sums[2 * stat + 1][c] / (float)n - mean * mean;
        float rstd = rsqrtf(fmaxf(var, 0.f) + BN_EPS);
        float g, bb, gate;
        if (stat == 0)      { g = bn_g[c]; bb = bn_b[c]; gate = 1.f; }
        else if (stat == 1) { g = pg0[c];  bb = pb0[c];  gate = gating[0 * NLAYERS + l]; }
        else                { g = pg1[c];  bb = pb1[c];  gate = gating[1 * NLAYERS + l]; }
        float S = g * rstd * gate;
        float T = (bb - mean * g * rstd) * gate;
        ST[stat * 128 + c] = S;
        ST[stat * 128 + 64 + c] = T;
    }
}

// ---------------- host ----------------

extern "C" void kernel_launch(void* const* d_in, const int* in_sizes, int n_in,
                              void* d_out, int out_size, void* d_ws, size_t ws_size,
                              hipStream_t stream) {
    const float* x      = (const float*)d_in[0];
    const int*   ei     = (const int*)d_in[1];
    const float* W      = (const float*)d_in[2];
    const float* bconv  = (const float*)d_in[3];
    const float* bn_g   = (const float*)d_in[4];
    const float* bn_b   = (const float*)d_in[5];
    const float* pw1    = (const float*)d_in[6];
    const float* pb1    = (const float*)d_in[7];
    const float* pw2    = (const float*)d_in[8];
    const float* pb2    = (const float*)d_in[9];
    const float* pbn_g  = (const float*)d_in[10];
    const float* pbn_b  = (const float*)d_in[11];
    const float* gating = (const float*)d_in[12];

    int n = in_sizes[0] / DIM;
    int E = in_sizes[1] / 2;
    int nb = (n + ROWS - 1) / ROWS;

    float* h_ws     = (float*)d_ws;
    float* aggr     = h_ws + (size_t)n * DIM;
    float* partials = aggr + (size_t)n * DIM;
    float* ST       = partials + (size_t)nb * 6 * DIM;
    int*   deg      = (int*)(ST + 6 * 128);
    int*   row_ptr  = deg + n;
    int*   csr      = row_ptr + n + 1;

    const int* esrc = ei;
    const int* edst = ei + E;

    // CSR build (amortized over the 5 layers; deterministic up to within-node order)
    hipMemsetAsync(deg, 0, (size_t)n * sizeof(int), stream);
    hist_k<<<(E + 255) / 256, 256, 0, stream>>>(edst, deg, E);
    scan_k<<<1, 1024, 0, stream>>>(deg, row_ptr, n);
    scatter_k<<<(E + 255) / 256, 256, 0, stream>>>(esrc, edst, deg, csr, E);

    hipMemcpyAsync(h_ws, x, (size_t)n * DIM * sizeof(float),
                   hipMemcpyDeviceToDevice, stream);

    for (int l = 0; l < NLAYERS; l++) {
        const float* Wl  = W     + (size_t)l * DIM * DIM;
        const float* bl  = bconv + (size_t)l * DIM;
        const float* bgl = bn_g  + (size_t)l * DIM;
        const float* bbl = bn_b  + (size_t)l * DIM;
        const float* p1a = pw1 + ((size_t)0 * NLAYERS + l) * DIM * BOT;
        const float* p1b = pw1 + ((size_t)1 * NLAYERS + l) * DIM * BOT;
        const float* b1a = pb1 + ((size_t)0 * NLAYERS + l) * BOT;
        const float* b1b = pb1 + ((size_t)1 * NLAYERS + l) * BOT;
        const float* p2a = pw2 + ((size_t)0 * NLAYERS + l) * BOT * DIM;
        const float* p2b = pw2 + ((size_t)1 * NLAYERS + l) * BOT * DIM;
        const float* b2a = pb2 + ((size_t)0 * NLAYERS + l) * DIM;
        const float* b2b = pb2 + ((size_t)1 * NLAYERS + l) * DIM;
        const float* g0  = pbn_g + ((size_t)0 * NLAYERS + l) * DIM;
        const float* g1  = pbn_g + ((size_t)1 * NLAYERS + l) * DIM;
        const float* be0 = pbn_b + ((size_t)0 * NLAYERS + l) * DIM;
        const float* be1 = pbn_b + ((size_t)1 * NLAYERS + l) * DIM;

        aggr_k<<<(n + 3) / 4, 256, 0, stream>>>(h_ws, row_ptr, csr, aggr, n);

        layer_k<0><<<nb, THREADS, 0, stream>>>(
            h_ws, aggr, Wl, bl, p1a, b1a, p2a, b2a, p1b, b1b, p2b, b2b,
            partials, nullptr, nullptr, n);

        reduce_k<<<1, 384, 0, stream>>>(partials, nb, n, bgl, bbl,
                                        g0, be0, g1, be1, gating, l, ST);

        if (l < NLAYERS - 1) {
            layer_k<2><<<nb, THREADS, 0, stream>>>(
                h_ws, aggr, Wl, bl, p1a, b1a, p2a, b2a, p1b, b1b, p2b, b2b,
                nullptr, ST, h_ws, n);
        } else {
            layer_k<1><<<nb, THREADS, 0, stream>>>(
                h_ws, aggr, Wl, bl, p1a, b1a, p2a, b2a, p1b, b1b, p2b, b2b,
                nullptr, ST, (float*)d_out, n);
        }
    }
}

// Round 2
// 981.617 us; speedup vs baseline: 3.1263x; 3.1263x over previous
//
#include <hip/hip_runtime.h>

#define DIM 64
#define BOT 15
#define NLAYERS 5
#define BN_EPS 1e-5f
#define ROWS 32
#define THREADS 256

// ---------------- CSR build ----------------

__global__ __launch_bounds__(256) void hist_k(const int* __restrict__ dst,
                                              int* __restrict__ deg, int E) {
    int e = blockIdx.x * blockDim.x + threadIdx.x;
    if (e < E) atomicAdd(&deg[dst[e]], 1);
}

// single-block exclusive scan; deg is read and overwritten with the exclusive
// prefix (used as the scatter cursor); row_ptr gets the same + row_ptr[n]=total
__global__ __launch_bounds__(1024) void scan_k(int* __restrict__ deg,
                                               int* __restrict__ row_ptr, int n) {
    __shared__ int buf[1024];
    __shared__ int carry_s;
    int t = threadIdx.x;
    if (t == 0) carry_s = 0;
    __syncthreads();
    for (int base = 0; base < n; base += 1024) {
        int idx = base + t;
        int v = (idx < n) ? deg[idx] : 0;
        buf[t] = v;
        __syncthreads();
        for (int off = 1; off < 1024; off <<= 1) {
            int x = (t >= off) ? buf[t - off] : 0;
            __syncthreads();
            buf[t] += x;
            __syncthreads();
        }
        int c = carry_s;
        int excl = c + buf[t] - v;
        if (idx < n) { row_ptr[idx] = excl; deg[idx] = excl; }
        int total = buf[1023];
        __syncthreads();
        if (t == 0) carry_s = c + total;
        __syncthreads();
    }
    if (t == 0) row_ptr[n] = carry_s;
}

__global__ __launch_bounds__(256) void scatter_k(const int* __restrict__ src,
                                                 const int* __restrict__ dst,
                                                 int* __restrict__ cursor,
                                                 int* __restrict__ csr, int E) {
    int e = blockIdx.x * blockDim.x + threadIdx.x;
    if (e < E) {
        int p = atomicAdd(&cursor[dst[e]], 1);
        csr[p] = src[e];
    }
}

// ---------------- aggregation: one wave per node, lane = feature ----------------

__global__ __launch_bounds__(256) void aggr_k(const float* __restrict__ h,
                                              const int* __restrict__ row_ptr,
                                              const int* __restrict__ csr,
                                              float* __restrict__ out, int n) {
    int gid = blockIdx.x * blockDim.x + threadIdx.x;
    int node = gid >> 6;
    int lane = gid & 63;
    if (node >= n) return;
    int s = row_ptr[node], e = row_ptr[node + 1];
    float acc = 0.f;
    int i = s;
    for (; i + 4 <= e; i += 4) {
        int a = csr[i], b = csr[i + 1], c = csr[i + 2], d = csr[i + 3];
        float v0 = h[a * DIM + lane];
        float v1 = h[b * DIM + lane];
        float v2 = h[c * DIM + lane];
        float v3 = h[d * DIM + lane];
        acc += (v0 + v1) + (v2 + v3);
    }
    for (; i < e; ++i) acc += h[csr[i] * DIM + lane];
    out[node * DIM + lane] = acc;
}

// ---------------- fused per-layer compute ----------------
// MODE 0: compute t0/a0/a1 per row, accumulate per-column sum & sumsq -> partials
// MODE 1: recompute, apply precombined BN scale/shift (ST), write out
// MODE 2: same as 1 + ReLU

template <int MODE>
__global__ __launch_bounds__(THREADS) void layer_k(
    const float* __restrict__ h, const float* __restrict__ aggr,
    const float* __restrict__ Wc, const float* __restrict__ bc,
    const float* __restrict__ p1a, const float* __restrict__ b1a,
    const float* __restrict__ p2a, const float* __restrict__ b2a,
    const float* __restrict__ p1b, const float* __restrict__ b1b,
    const float* __restrict__ p2b, const float* __restrict__ b2b,
    float* __restrict__ partials, const float* __restrict__ ST,
    float* __restrict__ hout, int n) {
    __shared__ float xh[ROWS][DIM + 1];   // +1 pad: kills 8-way bank conflict in k-loop
    __shared__ float xa[ROWS][DIM + 1];
    __shared__ float m0[ROWS][17];
    __shared__ float m1[ROWS][17];
    __shared__ float red[6][4][DIM];

    int t = threadIdx.x;
    int rowBase = blockIdx.x * ROWS;

    // phase 0: stage 32 rows of h and aggr (coalesced)
    #pragma unroll
    for (int i = 0; i < (ROWS * DIM) / THREADS; i++) {
        int idx = t + i * THREADS;
        int r = idx >> 6, c = idx & 63;
        int gr = rowBase + r;
        float vh = 0.f, va = 0.f;
        if (gr < n) { vh = h[(size_t)gr * DIM + c]; va = aggr[(size_t)gr * DIM + c]; }
        xh[r][c] = vh;
        xa[r][c] = va;
    }
    __syncthreads();

    // phase 1: adapter bottleneck mids: relu(x @ w1 + b1), 15 per row per branch
    {
        int r = t >> 3, sub = t & 7;
        #pragma unroll
        for (int half = 0; half < 2; half++) {
            int m = sub + half * 8;
            if (m < BOT) {
                float s0 = b1a[m], s1 = b1b[m];
                #pragma unroll
                for (int k = 0; k < DIM; k++) {
                    s0 = fmaf(xh[r][k], p1a[k * BOT + m], s0);
                    s1 = fmaf(xa[r][k], p1b[k * BOT + m], s1);
                }
                m0[r][m] = fmaxf(s0, 0.f);
                m1[r][m] = fmaxf(s1, 0.f);
            }
        }
    }
    __syncthreads();

    // phase 2: per-element conv + adapter outputs
    int col = t & 63;
    int rg = t >> 6;
    float sums[6] = {0.f, 0.f, 0.f, 0.f, 0.f, 0.f};
    float S0 = 0, T0 = 0, S1 = 0, T1 = 0, S2 = 0, T2 = 0;
    if (MODE != 0) {
        S0 = ST[col];        T0 = ST[64 + col];
        S1 = ST[128 + col];  T1 = ST[192 + col];
        S2 = ST[256 + col];  T2 = ST[320 + col];
    }
    #pragma unroll
    for (int i = 0; i < ROWS / 4; i++) {
        int r = rg + i * 4;
        int gr = rowBase + r;
        float s = bc[col];
        #pragma unroll
        for (int k = 0; k < DIM; k++) s = fmaf(xa[r][k], Wc[k * DIM + col], s);
        float u = b2a[col];
        #pragma unroll
        for (int m = 0; m < BOT; m++) u = fmaf(m0[r][m], p2a[m * DIM + col], u);
        float v = b2b[col];
        #pragma unroll
        for (int m = 0; m < BOT; m++) v = fmaf(m1[r][m], p2b[m * DIM + col], v);
        if (MODE == 0) {
            if (gr < n) {
                sums[0] += s; sums[1] += s * s;
                sums[2] += u; sums[3] += u * u;
                sums[4] += v; sums[5] += v * v;
            }
        } else {
            float r0 = fmaf(s, S0, T0) + fmaf(u, S1, T1) + fmaf(v, S2, T2);
            if (MODE == 2) r0 = fmaxf(r0, 0.f);
            if (gr < n) hout[(size_t)gr * DIM + col] = r0;
        }
    }

    if (MODE == 0) {
        #pragma unroll
        for (int j = 0; j < 6; j++) red[j][rg][col] = sums[j];
        __syncthreads();
        if (t < DIM) {
            #pragma unroll
            for (int j = 0; j < 6; j++) {
                float v = red[j][0][t] + red[j][1][t] + red[j][2][t] + red[j][3][t];
                partials[((size_t)blockIdx.x * 6 + j) * DIM + t] = v;
            }
        }
    }
}

// ---------------- parallel stats reduce + BN fold ----------------
// grid = 64 blocks (one per column); each block reduces all 6 stats over the
// nb per-block partials, then folds mean/var/gamma/beta/gating into per-column
// scale S and shift T:  bn(x)*gate = x*S + T
//   S = g*rstd*gate,  T = (b - mean*g*rstd)*gate

__global__ __launch_bounds__(256) void reduce_fold_k(
    const float* __restrict__ partials, int nb, int n,
    const float* __restrict__ bn_g, const float* __restrict__ bn_b,
    const float* __restrict__ pg0, const float* __restrict__ pb0,
    const float* __restrict__ pg1, const float* __restrict__ pb1,
    const float* __restrict__ gating, int l, float* __restrict__ ST) {
    __shared__ double red[6][256];
    int col = blockIdx.x;
    int t = threadIdx.x;
    double acc[6] = {0, 0, 0, 0, 0, 0};
    for (int b = t; b < nb; b += 256) {
        const float* p = partials + (size_t)b * 6 * DIM + col;
        #pragma unroll
        for (int j = 0; j < 6; j++) acc[j] += (double)p[j * DIM];
    }
    #pragma unroll
    for (int j = 0; j < 6; j++) red[j][t] = acc[j];
    __syncthreads();
    for (int off = 128; off > 0; off >>= 1) {
        if (t < off) {
            #pragma unroll
            for (int j = 0; j < 6; j++) red[j][t] += red[j][t + off];
        }
        __syncthreads();
    }
    if (t < 3) {
        int stat = t;
        float mean = (float)(red[2 * stat][0] / (double)n);
        float var = (float)(red[2 * stat + 1][0] / (double)n) - mean * mean;
        float rstd = rsqrtf(fmaxf(var, 0.f) + BN_EPS);
        float g, bb, gate;
        if (stat == 0)      { g = bn_g[col]; bb = bn_b[col]; gate = 1.f; }
        else if (stat == 1) { g = pg0[col];  bb = pb0[col];  gate = gating[0 * NLAYERS + l]; }
        else                { g = pg1[col];  bb = pb1[col];  gate = gating[1 * NLAYERS + l]; }
        float S = g * rstd * gate;
        float T = (bb - mean * g * rstd) * gate;
        ST[stat * 128 + col] = S;
        ST[stat * 128 + 64 + col] = T;
    }
}

// ---------------- host ----------------

extern "C" void kernel_launch(void* const* d_in, const int* in_sizes, int n_in,
                              void* d_out, int out_size, void* d_ws, size_t ws_size,
                              hipStream_t stream) {
    const float* x      = (const float*)d_in[0];
    const int*   ei     = (const int*)d_in[1];
    const float* W      = (const float*)d_in[2];
    const float* bconv  = (const float*)d_in[3];
    const float* bn_g   = (const float*)d_in[4];
    const float* bn_b   = (const float*)d_in[5];
    const float* pw1    = (const float*)d_in[6];
    const float* pb1    = (const float*)d_in[7];
    const float* pw2    = (const float*)d_in[8];
    const float* pb2    = (const float*)d_in[9];
    const float* pbn_g  = (const float*)d_in[10];
    const float* pbn_b  = (const float*)d_in[11];
    const float* gating = (const float*)d_in[12];

    int n = in_sizes[0] / DIM;
    int E = in_sizes[1] / 2;
    int nb = (n + ROWS - 1) / ROWS;

    float* h_ws     = (float*)d_ws;
    float* aggr     = h_ws + (size_t)n * DIM;
    float* partials = aggr + (size_t)n * DIM;
    float* ST       = partials + (size_t)nb * 6 * DIM;
    int*   deg      = (int*)(ST + 6 * 128);
    int*   row_ptr  = deg + n;
    int*   csr      = row_ptr + n + 1;

    const int* esrc = ei;
    const int* edst = ei + E;

    // CSR build (amortized over the 5 layers; deterministic up to within-node order)
    hipMemsetAsync(deg, 0, (size_t)n * sizeof(int), stream);
    hist_k<<<(E + 255) / 256, 256, 0, stream>>>(edst, deg, E);
    scan_k<<<1, 1024, 0, stream>>>(deg, row_ptr, n);
    scatter_k<<<(E + 255) / 256, 256, 0, stream>>>(esrc, edst, deg, csr, E);

    hipMemcpyAsync(h_ws, x, (size_t)n * DIM * sizeof(float),
                   hipMemcpyDeviceToDevice, stream);

    for (int l = 0; l < NLAYERS; l++) {
        const float* Wl  = W     + (size_t)l * DIM * DIM;
        const float* bl  = bconv + (size_t)l * DIM;
        const float* bgl = bn_g  + (size_t)l * DIM;
        const float* bbl = bn_b  + (size_t)l * DIM;
        const float* p1a = pw1 + ((size_t)0 * NLAYERS + l) * DIM * BOT;
        const float* p1b = pw1 + ((size_t)1 * NLAYERS + l) * DIM * BOT;
        const float* b1a = pb1 + ((size_t)0 * NLAYERS + l) * BOT;
        const float* b1b = pb1 + ((size_t)1 * NLAYERS + l) * BOT;
        const float* p2a = pw2 + ((size_t)0 * NLAYERS + l) * BOT * DIM;
        const float* p2b = pw2 + ((size_t)1 * NLAYERS + l) * BOT * DIM;
        const float* b2a = pb2 + ((size_t)0 * NLAYERS + l) * DIM;
        const float* b2b = pb2 + ((size_t)1 * NLAYERS + l) * DIM;
        const float* g0  = pbn_g + ((size_t)0 * NLAYERS + l) * DIM;
        const float* g1  = pbn_g + ((size_t)1 * NLAYERS + l) * DIM;
        const float* be0 = pbn_b + ((size_t)0 * NLAYERS + l) * DIM;
        const float* be1 = pbn_b + ((size_t)1 * NLAYERS + l) * DIM;

        aggr_k<<<(n + 3) / 4, 256, 0, stream>>>(h_ws, row_ptr, csr, aggr, n);

        layer_k<0><<<nb, THREADS, 0, stream>>>(
            h_ws, aggr, Wl, bl, p1a, b1a, p2a, b2a, p1b, b1b, p2b, b2b,
            partials, nullptr, nullptr, n);

        reduce_fold_k<<<DIM, 256, 0, stream>>>(partials, nb, n, bgl, bbl,
                                               g0, be0, g1, be1, gating, l, ST);

        if (l < NLAYERS - 1) {
            layer_k<2><<<nb, THREADS, 0, stream>>>(
                h_ws, aggr, Wl, bl, p1a, b1a, p2a, b2a, p1b, b1b, p2b, b2b,
                nullptr, ST, h_ws, n);
        } else {
            layer_k<1><<<nb, THREADS, 0, stream>>>(
                h_ws, aggr, Wl, bl, p1a, b1a, p2a, b2a, p1b, b1b, p2b, b2b,
                nullptr, ST, (float*)d_out, n);
        }
    }
}